// Round 9
// baseline (343.226 us; speedup 1.0000x reference)
//
#include <hip/hip_runtime.h>
#include <hip/hip_bf16.h>
#include <cstdint>
#include <cstddef>

typedef __bf16 bf16_t;
typedef __bf16 bf16x4 __attribute__((ext_vector_type(4)));
typedef __bf16 bf16x8 __attribute__((ext_vector_type(8)));
typedef float  f32x4  __attribute__((ext_vector_type(4)));

static constexpr int Bsz  = 4;
static constexpr int Nseq = 2048;
static constexpr int Dmod = 1024;
static constexpr int H    = 16;
static constexpr int DH   = 64;
static constexpr int M_TOT = Bsz * Nseq;  // 8192
static constexpr int K    = 1024;
static constexpr int BM = 128, BN = 128, BK = 32;

#define WAITVM(N) asm volatile("s_waitcnt vmcnt(" #N ")" ::: "memory")

__device__ __forceinline__ f32x4 mfma16(bf16x8 a, bf16x8 b, f32x4 c) {
  return __builtin_amdgcn_mfma_f32_16x16x32_bf16(a, b, c, 0, 0, 0);
}

__device__ __forceinline__ bf16x8 cvt8(const float* p) {
  f32x4 lo = *(const f32x4*)(p);
  f32x4 hi = *(const f32x4*)(p + 4);
  bf16x8 r;
#pragma unroll
  for (int i = 0; i < 4; ++i) { r[i] = (bf16_t)lo[i]; r[4 + i] = (bf16_t)hi[i]; }
  return r;
}

// async global->LDS, 16B per lane. LDS dest = wave-uniform base + lane*16.
__device__ __forceinline__ void async16(const void* g, void* l) {
  __builtin_amdgcn_global_load_lds(
      (const __attribute__((address_space(1))) void*)g,
      (__attribute__((address_space(3))) void*)l, 16, 0, 0);
}

// ---------------- f32 -> bf16 conversion (WEIGHTS ONLY now) ---------------
struct CvtArgs {
  const float* src[4];
  bf16_t* dst[4];
  int n;
};

__global__ __launch_bounds__(256) void cvt_kernel(CvtArgs a) {
  const int z = blockIdx.y;
  const float* s = a.src[z];
  bf16x8* d = (bf16x8*)a.dst[z];
  const int n8 = a.n >> 3;
  const int stride = gridDim.x * 256;
  for (int i = blockIdx.x * 256 + threadIdx.x; i < n8; i += stride)
    d[i] = cvt8(s + (size_t)i * 8);
}

// ---------------- tiled GEMM body v10: C = (A * W^T + b) * oscale ---------
// NEW vs R6:
//  * AF32=true: A staged as raw f32 into LDS (4 async16/thread), converted
//    to bf16 at fragment read. Eliminates the q/k/v cvt pass (~150MB HBM).
//  * chunk-XOR LDS swizzle BOTH-sides (rule #21): f32 A 8-chunk c^(r&7),
//    bf16 4-chunk c^(r&3). Per-32-lane-phase bank-uniform -> kills the
//    2x read conflict of the linear [128][32] layout (R6: 6.3M cycles).
//  * 2-slot depth-1: stage(it+1) issued BEFORE frag reads; WAITVM(0) after
//    MFMA (cover ~= reads+cvt+MFMA). qkv LDS 48KB (3 blk/CU), out 32KB (5).
// MODE 0: mfma(wf,af) (D.row=o), bf16 out [B,H,N,DH] (Q/K projections).
// MODE 1: mfma(af,wf), bf16 out [B,H,DH,N] (V^T projection).
// MODE 2: mfma(wf,af), f32 out [M,Dmod] (output projection, no bias).
template <int MODE, bool AF32, typename CT>
__device__ __forceinline__ void gemm_body2(
    void* AsRaw, bf16_t* Ws,
    const void* Av, const bf16_t* __restrict__ W,
    const float* __restrict__ bias, CT* __restrict__ C, float oscale) {
  const int tid  = threadIdx.x;
  const int lane = tid & 63;
  const int wave = tid >> 6;
  const int wm = wave & 1, wn = wave >> 1;
  const int row = lane & 15, quad = lane >> 4;
  const int m_blk = blockIdx.x * BM;
  const int n_blk = blockIdx.y * BN;

  float*  AsF = (float*)AsRaw;    // [2][128][32] f32 when AF32
  bf16_t* AsB = (bf16_t*)AsRaw;   // [2][128][32] bf16 otherwise
  const float*  Af = (const float*)Av;
  const bf16_t* Ab = (const bf16_t*)Av;

  f32x4 acc[4][4];
#pragma unroll
  for (int i = 0; i < 4; ++i)
#pragma unroll
    for (int j = 0; j < 4; ++j) acc[i][j] = (f32x4){0.f, 0.f, 0.f, 0.f};

  auto stageA = [&](int t, int s) {
    if constexpr (AF32) {
      // 1024 16B-chunks: g -> row r=g>>3, chunk c=g&7; src col pre-swizzled
#pragma unroll
      for (int j = 0; j < 4; ++j) {
        const int g = (j * 4 + wave) * 64 + lane;
        const int r = g >> 3, c = g & 7;
        async16(Af + (size_t)(m_blk + r) * K + t * BK + ((c ^ (r & 7)) * 4),
                AsF + s * 4096 + (j * 4 + wave) * 256);
      }
    } else {
      // 512 16B-chunks: r=g>>2, c=g&3
#pragma unroll
      for (int j = 0; j < 2; ++j) {
        const int g = (j * 4 + wave) * 64 + lane;
        const int r = g >> 2, c = g & 3;
        async16(Ab + (size_t)(m_blk + r) * K + t * BK + ((c ^ (r & 3)) * 8),
                AsB + s * 4096 + (j * 4 + wave) * 512);
      }
    }
  };
  auto stageW = [&](int t, int s) {
#pragma unroll
    for (int j = 0; j < 2; ++j) {
      const int g = (j * 4 + wave) * 64 + lane;
      const int r = g >> 2, c = g & 3;
      async16(W + (size_t)(n_blk + r) * K + t * BK + ((c ^ (r & 3)) * 8),
              Ws + s * 4096 + (j * 4 + wave) * 512);
    }
  };

  auto rdA = [&](int s, int i) -> bf16x8 {
    const int hr = wm * 64 + i * 16 + row;
    if constexpr (AF32) {
      const float* bp = AsF + s * 4096 + hr * 32;
      f32x4 lo = *(const f32x4*)(bp + (((2 * quad) ^ (hr & 7)) * 4));
      f32x4 hi = *(const f32x4*)(bp + (((2 * quad + 1) ^ (hr & 7)) * 4));
      bf16x8 o;
#pragma unroll
      for (int e = 0; e < 4; ++e) { o[e] = (bf16_t)lo[e]; o[4 + e] = (bf16_t)hi[e]; }
      return o;
    } else {
      return *(const bf16x8*)(AsB + s * 4096 + hr * 32 + (quad ^ (hr & 3)) * 8);
    }
  };
  auto rdW = [&](int s, int i) -> bf16x8 {
    const int hr = wn * 64 + i * 16 + row;
    return *(const bf16x8*)(Ws + s * 4096 + hr * 32 + (quad ^ (hr & 3)) * 8);
  };

  constexpr int NT = K / BK;  // 32

  stageA(0, 0); stageW(0, 0);
  WAITVM(0);
  __builtin_amdgcn_s_barrier();

#pragma unroll 1
  for (int it = 0; it < NT; ++it) {
    const int s = it & 1;
    if (it + 1 < NT) { stageA(it + 1, s ^ 1); stageW(it + 1, s ^ 1); }

    bf16x8 af[4], wf[4];
#pragma unroll
    for (int i = 0; i < 4; ++i) af[i] = rdA(s, i);
#pragma unroll
    for (int i = 0; i < 4; ++i) wf[i] = rdW(s, i);

    __builtin_amdgcn_s_setprio(1);
#pragma unroll
    for (int i = 0; i < 4; ++i)
#pragma unroll
      for (int j = 0; j < 4; ++j) {
        if (MODE == 1)
          acc[i][j] = mfma16(af[i], wf[j], acc[i][j]);
        else
          acc[i][j] = mfma16(wf[j], af[i], acc[i][j]);  // swapped: r -> o
      }
    __builtin_amdgcn_s_setprio(0);
    if (it + 1 < NT) WAITVM(0);
    __builtin_amdgcn_s_barrier();
  }

  if (MODE == 0) {
    // D.row(quad*4+r)=o, D.col(row)=m -> bf16x4 along od
#pragma unroll
    for (int i = 0; i < 4; ++i) {
      const int m = m_blk + wm * 64 + i * 16 + row;
      const int b = m >> 11, n = m & 2047;
#pragma unroll
      for (int j = 0; j < 4; ++j) {
        const int o0 = n_blk + wn * 64 + j * 16 + quad * 4;
        const int hh = o0 >> 6, od = o0 & 63;
        const f32x4 bv4 = *(const f32x4*)(bias + o0);
        const size_t idx0 = (((size_t)b * H + hh) * Nseq + n) * DH + od;
        bf16x4 pkt;
#pragma unroll
        for (int r = 0; r < 4; ++r)
          pkt[r] = (bf16_t)((acc[i][j][r] + bv4[r]) * oscale);
        *(bf16x4*)((bf16_t*)C + idx0) = pkt;
      }
    }
  } else if (MODE == 2) {
#pragma unroll
    for (int i = 0; i < 4; ++i) {
      const int m = m_blk + wm * 64 + i * 16 + row;
#pragma unroll
      for (int j = 0; j < 4; ++j) {
        const int o0 = n_blk + wn * 64 + j * 16 + quad * 4;
        *(f32x4*)((float*)C + (size_t)m * Dmod + o0) = acc[i][j];
      }
    }
  } else {  // MODE 1: V^T, D.col(row)=o, D.row(quad*4+r)=m -> bf16x4 along n
#pragma unroll
    for (int j = 0; j < 4; ++j) {
      const int o = n_blk + wn * 64 + j * 16 + row;
      const float bv = bias[o];
      const int hh = o >> 6, od = o & 63;
#pragma unroll
      for (int i = 0; i < 4; ++i) {
        const int m0 = m_blk + wm * 64 + i * 16 + quad * 4;
        const int b = m0 >> 11, n = m0 & 2047;
        const size_t idx0 = (((size_t)b * H + hh) * DH + od) * Nseq + n;
        bf16x4 pkt;
#pragma unroll
        for (int r = 0; r < 4; ++r)
          pkt[r] = (bf16_t)(acc[i][j][r] + bv);
        *(bf16x4*)((bf16_t*)C + idx0) = pkt;
      }
    }
  }
}

struct QkvArgs {
  const float*  A[3];     // raw f32 inputs q, k, v
  const bf16_t* W[3];
  const float*  bias[3];
  bf16_t*       out[3];
};

// fused Q/K/V projections: grid (64, 8, 3); A consumed as f32 directly.
__global__ __launch_bounds__(256) void qkv_gemm(QkvArgs a, float qscale) {
  __shared__ __align__(16) float  AsF[2][128][32];   // 32 KB
  __shared__ __align__(16) bf16_t Ws2[2][128][32];   // 16 KB
  const int z = blockIdx.z;
  if (z == 2)
    gemm_body2<1, true, bf16_t>(AsF, &Ws2[0][0][0], a.A[2], a.W[2], a.bias[2],
                                a.out[2], 1.f);
  else if (z == 1)
    gemm_body2<0, true, bf16_t>(AsF, &Ws2[0][0][0], a.A[1], a.W[1], a.bias[1],
                                a.out[1], 1.f);
  else
    gemm_body2<0, true, bf16_t>(AsF, &Ws2[0][0][0], a.A[0], a.W[0], a.bias[0],
                                a.out[0], qscale);
}

__global__ __launch_bounds__(256) void out_gemm(
    const bf16_t* __restrict__ A, const bf16_t* __restrict__ W,
    float* __restrict__ C) {
  __shared__ __align__(16) bf16_t AsB[2][128][32];   // 16 KB
  __shared__ __align__(16) bf16_t Ws2[2][128][32];   // 16 KB
  gemm_body2<2, false, float>(AsB, &Ws2[0][0][0], A, W, nullptr, C, 1.f);
}

// ---------------- flash attention v9 (unchanged from R7) -----------------
// Q,K: [B,H,N,64] (Q pre-scaled by 0.125*log2e); VT: [B,H,64,N]; X: [B,N,D]
__global__ __launch_bounds__(256, 4) void attn_fwd(
    const bf16_t* __restrict__ Q, const bf16_t* __restrict__ Kh,
    const bf16_t* __restrict__ VT, bf16_t* __restrict__ X) {
  const int lane = threadIdx.x & 63;
  const int wave = threadIdx.x >> 6;
  const int bid = blockIdx.x;  // 0..2047
  const int bh = (bid & 7) * 8 + ((bid >> 3) & 7);
  const int qt = 31 - (bid >> 6);
  const int b = bh >> 4, h = bh & 15;
  const int row = lane & 15, quad = lane >> 4;

  __shared__ __align__(16) bf16_t Kt[3][32][64];
  __shared__ __align__(16) bf16_t Vt[3][64][32];
  __shared__ __align__(16) bf16_t plds[4][16][56];  // stride 112B

  const bf16_t* Qb = Q + (size_t)bh * Nseq * DH;
  const bf16_t* Kb = Kh + (size_t)bh * Nseq * DH;
  const bf16_t* Vb = VT + (size_t)bh * DH * Nseq;

  const int krow_l = lane >> 3;
  const int kc8    = lane & 7;
  const bf16_t* ksrc =
      Kb + (size_t)(wave * 8 + krow_l) * DH + (kc8 ^ krow_l) * 8;
  bf16_t* kdst = &Kt[0][wave * 8][0];

  const int vd_l = lane >> 2;
  const int vkc  = lane & 3;
  const int vd   = wave * 16 + vd_l;
  const bf16_t* vsrc =
      Vb + (size_t)vd * Nseq + (vkc ^ ((vd_l >> 1) & 3)) * 8;
  bf16_t* vdst = &Vt[0][wave * 16][0];

  auto stage = [&](int t, int buf) {
    async16(ksrc + (size_t)t * (32 * DH), kdst + buf * (32 * 64));
    async16(vsrc + t * 32, vdst + buf * (64 * 32));
  };

  const int q0 = qt * 64 + wave * 16;
  const int qg = q0 + row;

  bf16x8 qf0 = *(const bf16x8*)(Qb + (size_t)(q0 + row) * DH + quad * 8);
  bf16x8 qf1 = *(const bf16x8*)(Qb + (size_t)(q0 + row) * DH + 32 + quad * 8);

  f32x4 o_acc[4];
#pragma unroll
  for (int c = 0; c < 4; ++c) o_acc[c] = (f32x4){0.f, 0.f, 0.f, 0.f};
  f32x4 lsv = (f32x4){0.f, 0.f, 0.f, 0.f};

  const int nfull = 2 * qt;
  const int NT = nfull + 2;  // even, >= 2

  auto read_kf = [&](bf16x8 (&kf)[2][2], int bfv) {
#pragma unroll
    for (int c = 0; c < 2; ++c)
#pragma unroll
      for (int hf = 0; hf < 2; ++hf)
        kf[c][hf] = *(const bf16x8*)(
            &Kt[bfv][c * 16 + row][((hf * 4 + quad) ^ (row & 7)) * 8]);
  };
  auto read_vf = [&](bf16x8 (&vf)[4], int bfv) {
#pragma unroll
    for (int ch = 0; ch < 4; ++ch)
      vf[ch] = *(const bf16x8*)(
          &Vt[bfv][ch * 16 + row][(quad ^ ((row >> 1) & 3)) * 8]);
  };
  auto qk = [&](f32x4 (&s)[2], const bf16x8 (&kf)[2][2]) {
    __builtin_amdgcn_s_setprio(1);
#pragma unroll
    for (int c = 0; c < 2; ++c) {
      s[c] = (f32x4){0.f, 0.f, 0.f, 0.f};
      s[c] = mfma16(kf[c][0], qf0, s[c]);
      s[c] = mfma16(kf[c][1], qf1, s[c]);
    }
    __builtin_amdgcn_s_setprio(0);
  };
  auto pv = [&](const bf16x8& pf, const bf16x8 (&vf)[4]) {
    __builtin_amdgcn_s_setprio(1);
#pragma unroll
    for (int ch = 0; ch < 4; ++ch)
      o_acc[ch] = mfma16(pf, vf[ch], o_acc[ch]);
    __builtin_amdgcn_s_setprio(0);
  };
  auto softmax_store = [&](const f32x4 (&s)[2], int it, bf16x8& pfN) {
    const bool mask = (it >= nfull);
    const int k0 = it * 32;
#pragma unroll
    for (int c = 0; c < 2; ++c) {
      bf16x4 pk;
      f32x4 pv4;
#pragma unroll
      for (int r = 0; r < 4; ++r) {
        float t = s[c][r];
        if (mask) {
          const int kg = k0 + c * 16 + quad * 4 + r;
          t = (kg <= qg) ? t : -1e38f;
        }
        float p = __builtin_amdgcn_exp2f(t);
        pv4[r] = p;
        pk[r] = (bf16_t)p;
      }
      lsv += pv4;
      *(bf16x4*)(&plds[wave][row][c * 16 + quad * 4]) = pk;
    }
    asm volatile("" ::: "memory");
    pfN = *(const bf16x8*)(&plds[wave][row][quad * 8]);
  };

  bf16x8 vfA[4], vfB[4], pfA, pfB;

  stage(0, 0);
  stage(1, 1);

  // ---- prologue: tile 0 (no PV yet) ----
  {
    WAITVM(2);
    __builtin_amdgcn_s_barrier();
    bf16x8 kf[2][2];
    read_kf(kf, 0);
    read_vf(vfA, 0);
    if (NT > 2) stage(2, 2);
    f32x4 s[2];
    qk(s, kf);
    softmax_store(s, 0, pfA);
  }

  int buf = 1, bufn = (NT > 2) ? 0 : 2;

#pragma unroll 1
  for (int it = 1; it + 1 < NT; it += 2) {
    {
      WAITVM(2);
      __builtin_amdgcn_s_barrier();
      bf16x8 kf[2][2];
      read_kf(kf, buf);
      read_vf(vfB, buf);
      if (it + 2 < NT) stage(it + 2, bufn);
      f32x4 s[2];
      qk(s, kf);
      pv(pfA, vfA);
      softmax_store(s, it, pfB);
      buf  = (buf  == 2) ? 0 : buf  + 1;
      bufn = (bufn == 2) ? 0 : bufn + 1;
    }
    {
      WAITVM(2);
      __builtin_amdgcn_s_barrier();
      bf16x8 kf[2][2];
      read_kf(kf, buf);
      read_vf(vfA, buf);
      if (it + 3 < NT) stage(it + 3, bufn);
      f32x4 s[2];
      qk(s, kf);
      pv(pfB, vfB);
      softmax_store(s, it + 1, pfA);
      buf  = (buf  == 2) ? 0 : buf  + 1;
      bufn = (bufn == 2) ? 0 : bufn + 1;
    }
  }

  {
    WAITVM(0);
    __builtin_amdgcn_s_barrier();
    bf16x8 kf[2][2];
    read_kf(kf, buf);
    read_vf(vfB, buf);
    f32x4 s[2];
    qk(s, kf);
    pv(pfA, vfA);
    softmax_store(s, NT - 1, pfB);
  }
  pv(pfB, vfB);

  float ls = (lsv[0] + lsv[1]) + (lsv[2] + lsv[3]);
  ls += __shfl_xor(ls, 16, 64);
  ls += __shfl_xor(ls, 32, 64);

#pragma unroll
  for (int r = 0; r < 4; ++r) {
    const float linv = 1.f / __shfl(ls, quad * 4 + r, 64);
    const int qq = q0 + quad * 4 + r;
    const size_t base = ((size_t)b * Nseq + qq) * Dmod + h * DH;
#pragma unroll
    for (int ch = 0; ch < 4; ++ch)
      X[base + ch * 16 + row] = (bf16_t)(o_acc[ch][r] * linv);
  }
}

extern "C" void kernel_launch(void* const* d_in, const int* in_sizes, int n_in,
                              void* d_out, int out_size, void* d_ws,
                              size_t ws_size, hipStream_t stream) {
  const float* q  = (const float*)d_in[0];
  const float* k  = (const float*)d_in[1];
  const float* v  = (const float*)d_in[2];
  const float* Wq = (const float*)d_in[3];
  const float* bq = (const float*)d_in[4];
  const float* Wk = (const float*)d_in[5];
  const float* bk = (const float*)d_in[6];
  const float* Wv = (const float*)d_in[7];
  const float* bv = (const float*)d_in[8];
  const float* Wo = (const float*)d_in[9];
  float* out = (float*)d_out;

  const size_t E  = (size_t)M_TOT * Dmod;   // 8M elems
  const size_t EW = (size_t)Dmod * Dmod;    // 1M elems
  bf16_t* ws = (bf16_t*)d_ws;
  bf16_t* Wqb = ws;
  bf16_t* Wkb = Wqb + EW;
  bf16_t* Wvb = Wkb + EW;
  bf16_t* Wob = Wvb + EW;
  bf16_t* Qh  = Wob + EW;
  bf16_t* Kh  = Qh + E;
  bf16_t* VT  = Kh + E;
  bf16_t* X   = VT + E;

  CvtArgs ca;
  ca.src[0] = Wq; ca.dst[0] = Wqb;
  ca.src[1] = Wk; ca.dst[1] = Wkb;
  ca.src[2] = Wv; ca.dst[2] = Wvb;
  ca.src[3] = Wo; ca.dst[3] = Wob;
  ca.n = (int)EW;
  cvt_kernel<<<dim3(256, 4), 256, 0, stream>>>(ca);

  const float C_SC = 0.125f * 1.44269504088896f;  // scale * log2(e) -> into Q

  QkvArgs qa;
  qa.A[0] = q; qa.W[0] = Wqb; qa.bias[0] = bq; qa.out[0] = Qh;
  qa.A[1] = k; qa.W[1] = Wkb; qa.bias[1] = bk; qa.out[1] = Kh;
  qa.A[2] = v; qa.W[2] = Wvb; qa.bias[2] = bv; qa.out[2] = VT;
  qkv_gemm<<<dim3(M_TOT / BM, Dmod / BN, 3), dim3(256), 0, stream>>>(qa, C_SC);

  attn_fwd<<<dim3(2048), dim3(256), 0, stream>>>(Qh, Kh, VT, X);

  out_gemm<<<dim3(M_TOT / BM, Dmod / BN), dim3(256), 0, stream>>>(X, Wob, out);
}

// Round 10
// 312.986 us; speedup vs baseline: 1.0966x; 1.0966x over previous
//
#include <hip/hip_runtime.h>
#include <hip/hip_bf16.h>
#include <cstdint>
#include <cstddef>

typedef __bf16 bf16_t;
typedef __bf16 bf16x4 __attribute__((ext_vector_type(4)));
typedef __bf16 bf16x8 __attribute__((ext_vector_type(8)));
typedef float  f32x4  __attribute__((ext_vector_type(4)));

static constexpr int Bsz  = 4;
static constexpr int Nseq = 2048;
static constexpr int Dmod = 1024;
static constexpr int H    = 16;
static constexpr int DH   = 64;
static constexpr int M_TOT = Bsz * Nseq;  // 8192
static constexpr int K    = 1024;
static constexpr int BM = 128, BN = 128, BK = 32;

// counted vmcnt wait (T4): never drain to 0 in steady state
#define WAITVM(N) asm volatile("s_waitcnt vmcnt(" #N ")" ::: "memory")

__device__ __forceinline__ f32x4 mfma16(bf16x8 a, bf16x8 b, f32x4 c) {
  return __builtin_amdgcn_mfma_f32_16x16x32_bf16(a, b, c, 0, 0, 0);
}

__device__ __forceinline__ bf16x8 cvt8(const float* p) {
  f32x4 lo = *(const f32x4*)(p);
  f32x4 hi = *(const f32x4*)(p + 4);
  bf16x8 r;
#pragma unroll
  for (int i = 0; i < 4; ++i) { r[i] = (bf16_t)lo[i]; r[4 + i] = (bf16_t)hi[i]; }
  return r;
}

// async global->LDS, 16B per lane. LDS dest = wave-uniform base + lane*16.
__device__ __forceinline__ void async16(const bf16_t* g, bf16_t* l) {
  __builtin_amdgcn_global_load_lds(
      (const __attribute__((address_space(1))) void*)g,
      (__attribute__((address_space(3))) void*)l, 16, 0, 0);
}

// ---------------- f32 -> bf16 conversion pass ----------------
struct CvtArgs {
  const float* src[7];
  bf16_t* dst[7];
  int n[7];
};

__global__ __launch_bounds__(256) void cvt_kernel(CvtArgs a) {
  const int z = blockIdx.y;
  const float* s = a.src[z];
  bf16x8* d = (bf16x8*)a.dst[z];
  const int n8 = a.n[z] >> 3;
  const int stride = gridDim.x * 256;
  for (int i = blockIdx.x * 256 + threadIdx.x; i < n8; i += stride)
    d[i] = cvt8(s + (size_t)i * 8);
}

// ---------------- tiled bf16 GEMM body: C = (A * W^T + b) * oscale --------
// 3-buffer depth-2 pipeline, ONE s_barrier per K-step, counted vmcnt(4)
// (T4, m201-verified pattern; R6: 712 TF, MfmaUtil 29.5). R9's depth-1 +
// f32-A variant regressed 2x (pipeline drain re-exposed; swizzle wrong) —
// this is the R6/R7 best-known-good, restored byte-identical.
// MODE 0: swapped mfma (D.row=o), bf16 out [B,H,N,DH] (Q/K projections).
// MODE 1: original orientation, bf16 out [B,H,DH,N] (V^T projection).
// MODE 2: swapped, f32 out [M, Dmod] (output projection, no bias).
template <int MODE, typename CT>
__device__ __forceinline__ void gemm_body(
    bf16_t (*As)[BM][BK], bf16_t (*Ws)[BN][BK],
    const bf16_t* __restrict__ A, const bf16_t* __restrict__ W,
    const float* __restrict__ bias, CT* __restrict__ C, float oscale) {
  const int tid  = threadIdx.x;
  const int lane = tid & 63;
  const int wave = tid >> 6;
  const int wm = wave & 1, wn = wave >> 1;
  const int row = lane & 15, quad = lane >> 4;

  const int m_blk = blockIdx.x * BM;
  const int n_blk = blockIdx.y * BN;

  f32x4 acc[4][4];
#pragma unroll
  for (int i = 0; i < 4; ++i)
#pragma unroll
    for (int j = 0; j < 4; ++j) acc[i][j] = (f32x4){0.f, 0.f, 0.f, 0.f};

  const int srow = lane >> 2;
  const int scol = (lane & 3) * 8;

  const bf16_t* Abase = A + (size_t)m_blk * K + scol;
  const bf16_t* Wbase = W + (size_t)n_blk * K + scol;

  constexpr int NT = K / BK;  // 32

  auto stage = [&](int t, int buf) {
#pragma unroll
    for (int j = 0; j < 2; ++j) {
      const int seg = wave * 2 + j;
      async16(Abase + (size_t)(seg * 16 + srow) * K + t * BK,
              &As[buf][seg * 16][0]);
      async16(Wbase + (size_t)(seg * 16 + srow) * K + t * BK,
              &Ws[buf][seg * 16][0]);
    }
  };

  stage(0, 0);
  stage(1, 1);
  int buf = 0, bufn = 2;

#pragma unroll 1
  for (int it = 0; it < NT; ++it) {
    // drain tile it's 4 loads; keep tile it+1's 4 in flight across barrier
    if (it + 1 < NT) { WAITVM(4); } else { WAITVM(0); }
    __builtin_amdgcn_s_barrier();

    bf16x8 af[4], wf[4];
#pragma unroll
    for (int i = 0; i < 4; ++i)
      af[i] = *(const bf16x8*)(&As[buf][wm * 64 + i * 16 + row][quad * 8]);
#pragma unroll
    for (int i = 0; i < 4; ++i)
      wf[i] = *(const bf16x8*)(&Ws[buf][wn * 64 + i * 16 + row][quad * 8]);

    if (it + 2 < NT) stage(it + 2, bufn);

#pragma unroll
    for (int i = 0; i < 4; ++i)
#pragma unroll
      for (int j = 0; j < 4; ++j) {
        if (MODE == 1)
          acc[i][j] = mfma16(af[i], wf[j], acc[i][j]);
        else
          acc[i][j] = mfma16(wf[j], af[i], acc[i][j]);  // swapped: r -> o
      }

    buf  = (buf  == 2) ? 0 : buf  + 1;
    bufn = (bufn == 2) ? 0 : bufn + 1;
  }

  if (MODE == 0) {
    // D.row(quad*4+r) = o (output feature), D.col(lane&15=row) = m
#pragma unroll
    for (int i = 0; i < 4; ++i) {
      const int m = m_blk + wm * 64 + i * 16 + row;
      const int b = m >> 11, n = m & 2047;
#pragma unroll
      for (int j = 0; j < 4; ++j) {
        const int o0 = n_blk + wn * 64 + j * 16 + quad * 4;
        const int hh = o0 >> 6, od = o0 & 63;
        const f32x4 bv4 = *(const f32x4*)(bias + o0);
        const size_t idx0 = (((size_t)b * H + hh) * Nseq + n) * DH + od;
        bf16x4 pkt;
#pragma unroll
        for (int r = 0; r < 4; ++r)
          pkt[r] = (bf16_t)((acc[i][j][r] + bv4[r]) * oscale);
        *(bf16x4*)((bf16_t*)C + idx0) = pkt;
      }
    }
  } else if (MODE == 2) {
#pragma unroll
    for (int i = 0; i < 4; ++i) {
      const int m = m_blk + wm * 64 + i * 16 + row;
#pragma unroll
      for (int j = 0; j < 4; ++j) {
        const int o0 = n_blk + wn * 64 + j * 16 + quad * 4;
        *(f32x4*)((float*)C + (size_t)m * Dmod + o0) = acc[i][j];
      }
    }
  } else {  // MODE 1: V^T, original orientation, contiguous n over r
#pragma unroll
    for (int j = 0; j < 4; ++j) {
      const int o = n_blk + wn * 64 + j * 16 + row;
      const float bv = bias[o];
      const int hh = o >> 6, od = o & 63;
#pragma unroll
      for (int i = 0; i < 4; ++i) {
        const int m0 = m_blk + wm * 64 + i * 16 + quad * 4;
        const int b = m0 >> 11, n = m0 & 2047;
        const size_t idx0 = (((size_t)b * H + hh) * DH + od) * Nseq + n;
        bf16x4 pkt;
#pragma unroll
        for (int r = 0; r < 4; ++r)
          pkt[r] = (bf16_t)(acc[i][j][r] + bv);
        *(bf16x4*)((bf16_t*)C + idx0) = pkt;
      }
    }
  }
}

struct QkvArgs {
  const bf16_t* A[3];
  const bf16_t* W[3];
  const float*  bias[3];
  bf16_t*       out[3];
};

// fused Q/K/V projections: grid (64, 8, 3); z=0 Q (scaled), z=1 K, z=2 V^T.
__global__ __launch_bounds__(256) void qkv_gemm(QkvArgs a, float qscale) {
  __shared__ bf16_t As[3][BM][BK];
  __shared__ bf16_t Ws[3][BN][BK];
  const int z = blockIdx.z;
  if (z == 2)
    gemm_body<1, bf16_t>(As, Ws, a.A[2], a.W[2], a.bias[2], a.out[2], 1.f);
  else if (z == 1)
    gemm_body<0, bf16_t>(As, Ws, a.A[1], a.W[1], a.bias[1], a.out[1], 1.f);
  else
    gemm_body<0, bf16_t>(As, Ws, a.A[0], a.W[0], a.bias[0], a.out[0], qscale);
}

__global__ __launch_bounds__(256) void out_gemm(
    const bf16_t* __restrict__ A, const bf16_t* __restrict__ W,
    float* __restrict__ C) {
  __shared__ bf16_t As[3][BM][BK];
  __shared__ bf16_t Ws[3][BN][BK];
  gemm_body<2, float>(As, Ws, A, W, nullptr, C, 1.f);
}

// ---------------- flash attention v9 (R7 best-known-good) ----------------
// Q,K: [B,H,N,64] (Q pre-scaled by 0.125*log2e); VT: [B,H,64,N]; X: [B,N,D]
// Cross-tile software pipeline of the P LDS round-trip: P(it) write+readback
// issued back-to-back (same-wave DS ops in order); pf(it) consumed one tile
// later under tile it+1's ds_reads + QK MFMAs.
__global__ __launch_bounds__(256, 4) void attn_fwd(
    const bf16_t* __restrict__ Q, const bf16_t* __restrict__ Kh,
    const bf16_t* __restrict__ VT, bf16_t* __restrict__ X) {
  const int lane = threadIdx.x & 63;
  const int wave = threadIdx.x >> 6;
  const int bid = blockIdx.x;  // 0..2047
  const int bh = (bid & 7) * 8 + ((bid >> 3) & 7);
  const int qt = 31 - (bid >> 6);
  const int b = bh >> 4, h = bh & 15;
  const int row = lane & 15, quad = lane >> 4;

  __shared__ __align__(16) bf16_t Kt[3][32][64];
  __shared__ __align__(16) bf16_t Vt[3][64][32];
  __shared__ __align__(16) bf16_t plds[4][16][56];  // stride 112B

  const bf16_t* Qb = Q + (size_t)bh * Nseq * DH;
  const bf16_t* Kb = Kh + (size_t)bh * Nseq * DH;
  const bf16_t* Vb = VT + (size_t)bh * DH * Nseq;

  const int krow_l = lane >> 3;
  const int kc8    = lane & 7;
  const bf16_t* ksrc =
      Kb + (size_t)(wave * 8 + krow_l) * DH + (kc8 ^ krow_l) * 8;
  bf16_t* kdst = &Kt[0][wave * 8][0];

  const int vd_l = lane >> 2;
  const int vkc  = lane & 3;
  const int vd   = wave * 16 + vd_l;
  const bf16_t* vsrc =
      Vb + (size_t)vd * Nseq + (vkc ^ ((vd_l >> 1) & 3)) * 8;
  bf16_t* vdst = &Vt[0][wave * 16][0];

  auto stage = [&](int t, int buf) {
    async16(ksrc + (size_t)t * (32 * DH), kdst + buf * (32 * 64));
    async16(vsrc + t * 32, vdst + buf * (64 * 32));
  };

  const int q0 = qt * 64 + wave * 16;
  const int qg = q0 + row;

  bf16x8 qf0 = *(const bf16x8*)(Qb + (size_t)(q0 + row) * DH + quad * 8);
  bf16x8 qf1 = *(const bf16x8*)(Qb + (size_t)(q0 + row) * DH + 32 + quad * 8);

  f32x4 o_acc[4];
#pragma unroll
  for (int c = 0; c < 4; ++c) o_acc[c] = (f32x4){0.f, 0.f, 0.f, 0.f};
  f32x4 lsv = (f32x4){0.f, 0.f, 0.f, 0.f};

  const int nfull = 2 * qt;
  const int NT = nfull + 2;  // even, >= 2

  auto read_kf = [&](bf16x8 (&kf)[2][2], int bfv) {
#pragma unroll
    for (int c = 0; c < 2; ++c)
#pragma unroll
      for (int hf = 0; hf < 2; ++hf)
        kf[c][hf] = *(const bf16x8*)(
            &Kt[bfv][c * 16 + row][((hf * 4 + quad) ^ (row & 7)) * 8]);
  };
  auto read_vf = [&](bf16x8 (&vf)[4], int bfv) {
#pragma unroll
    for (int ch = 0; ch < 4; ++ch)
      vf[ch] = *(const bf16x8*)(
          &Vt[bfv][ch * 16 + row][(quad ^ ((row >> 1) & 3)) * 8]);
  };
  auto qk = [&](f32x4 (&s)[2], const bf16x8 (&kf)[2][2]) {
    __builtin_amdgcn_s_setprio(1);
#pragma unroll
    for (int c = 0; c < 2; ++c) {
      s[c] = (f32x4){0.f, 0.f, 0.f, 0.f};
      s[c] = mfma16(kf[c][0], qf0, s[c]);
      s[c] = mfma16(kf[c][1], qf1, s[c]);
    }
    __builtin_amdgcn_s_setprio(0);
  };
  auto pv = [&](const bf16x8& pf, const bf16x8 (&vf)[4]) {
    __builtin_amdgcn_s_setprio(1);
#pragma unroll
    for (int ch = 0; ch < 4; ++ch)
      o_acc[ch] = mfma16(pf, vf[ch], o_acc[ch]);
    __builtin_amdgcn_s_setprio(0);
  };
  auto softmax_store = [&](const f32x4 (&s)[2], int it, bf16x8& pfN) {
    const bool mask = (it >= nfull);
    const int k0 = it * 32;
#pragma unroll
    for (int c = 0; c < 2; ++c) {
      bf16x4 pk;
      f32x4 pv4;
#pragma unroll
      for (int r = 0; r < 4; ++r) {
        float t = s[c][r];
        if (mask) {
          const int kg = k0 + c * 16 + quad * 4 + r;
          t = (kg <= qg) ? t : -1e38f;
        }
        float p = __builtin_amdgcn_exp2f(t);
        pv4[r] = p;
        pk[r] = (bf16_t)p;
      }
      lsv += pv4;
      *(bf16x4*)(&plds[wave][row][c * 16 + quad * 4]) = pk;
    }
    asm volatile("" ::: "memory");
    pfN = *(const bf16x8*)(&plds[wave][row][quad * 8]);
  };

  bf16x8 vfA[4], vfB[4], pfA, pfB;

  stage(0, 0);
  stage(1, 1);

  // ---- prologue: tile 0 (no PV yet) ----
  {
    WAITVM(2);
    __builtin_amdgcn_s_barrier();
    bf16x8 kf[2][2];
    read_kf(kf, 0);
    read_vf(vfA, 0);
    if (NT > 2) stage(2, 2);
    f32x4 s[2];
    qk(s, kf);
    softmax_store(s, 0, pfA);
  }

  int buf = 1, bufn = (NT > 2) ? 0 : 2;

#pragma unroll 1
  for (int it = 1; it + 1 < NT; it += 2) {
    {
      WAITVM(2);
      __builtin_amdgcn_s_barrier();
      bf16x8 kf[2][2];
      read_kf(kf, buf);
      read_vf(vfB, buf);
      if (it + 2 < NT) stage(it + 2, bufn);
      f32x4 s[2];
      qk(s, kf);
      pv(pfA, vfA);
      softmax_store(s, it, pfB);
      buf  = (buf  == 2) ? 0 : buf  + 1;
      bufn = (bufn == 2) ? 0 : bufn + 1;
    }
    {
      WAITVM(2);
      __builtin_amdgcn_s_barrier();
      bf16x8 kf[2][2];
      read_kf(kf, buf);
      read_vf(vfA, buf);
      if (it + 3 < NT) stage(it + 3, bufn);
      f32x4 s[2];
      qk(s, kf);
      pv(pfB, vfB);
      softmax_store(s, it + 1, pfA);
      buf  = (buf  == 2) ? 0 : buf  + 1;
      bufn = (bufn == 2) ? 0 : bufn + 1;
    }
  }

  {
    WAITVM(0);
    __builtin_amdgcn_s_barrier();
    bf16x8 kf[2][2];
    read_kf(kf, buf);
    read_vf(vfB, buf);
    f32x4 s[2];
    qk(s, kf);
    pv(pfA, vfA);
    softmax_store(s, NT - 1, pfB);
  }
  pv(pfB, vfB);

  float ls = (lsv[0] + lsv[1]) + (lsv[2] + lsv[3]);
  ls += __shfl_xor(ls, 16, 64);
  ls += __shfl_xor(ls, 32, 64);

#pragma unroll
  for (int r = 0; r < 4; ++r) {
    const float linv = 1.f / __shfl(ls, quad * 4 + r, 64);
    const int qq = q0 + quad * 4 + r;
    const size_t base = ((size_t)b * Nseq + qq) * Dmod + h * DH;
#pragma unroll
    for (int ch = 0; ch < 4; ++ch)
      X[base + ch * 16 + row] = (bf16_t)(o_acc[ch][r] * linv);
  }
}

extern "C" void kernel_launch(void* const* d_in, const int* in_sizes, int n_in,
                              void* d_out, int out_size, void* d_ws,
                              size_t ws_size, hipStream_t stream) {
  const float* q  = (const float*)d_in[0];
  const float* k  = (const float*)d_in[1];
  const float* v  = (const float*)d_in[2];
  const float* Wq = (const float*)d_in[3];
  const float* bq = (const float*)d_in[4];
  const float* Wk = (const float*)d_in[5];
  const float* bk = (const float*)d_in[6];
  const float* Wv = (const float*)d_in[7];
  const float* bv = (const float*)d_in[8];
  const float* Wo = (const float*)d_in[9];
  float* out = (float*)d_out;

  const size_t E  = (size_t)M_TOT * Dmod;   // 8M elems
  const size_t EW = (size_t)Dmod * Dmod;    // 1M elems
  bf16_t* ws = (bf16_t*)d_ws;
  bf16_t* qb  = ws;
  bf16_t* kb  = ws + E;
  bf16_t* vb  = ws + 2 * E;
  bf16_t* Wqb = ws + 3 * E;
  bf16_t* Wkb = Wqb + EW;
  bf16_t* Wvb = Wkb + EW;
  bf16_t* Wob = Wvb + EW;
  bf16_t* Qh  = Wob + EW;
  bf16_t* Kh  = Qh + E;
  bf16_t* VT  = Kh + E;
  bf16_t* X   = kb;  // kb dead after K projection; reuse for attn output

  CvtArgs ca;
  ca.src[0] = q;  ca.dst[0] = qb;  ca.n[0] = (int)E;
  ca.src[1] = k;  ca.dst[1] = kb;  ca.n[1] = (int)E;
  ca.src[2] = v;  ca.dst[2] = vb;  ca.n[2] = (int)E;
  ca.src[3] = Wq; ca.dst[3] = Wqb; ca.n[3] = (int)EW;
  ca.src[4] = Wk; ca.dst[4] = Wkb; ca.n[4] = (int)EW;
  ca.src[5] = Wv; ca.dst[5] = Wvb; ca.n[5] = (int)EW;
  ca.src[6] = Wo; ca.dst[6] = Wob; ca.n[6] = (int)EW;
  cvt_kernel<<<dim3(512, 7), 256, 0, stream>>>(ca);

  const float C_SC = 0.125f * 1.44269504088896f;  // scale * log2(e) -> into Q

  dim3 blk(256);
  QkvArgs qa;
  qa.A[0] = qb; qa.W[0] = Wqb; qa.bias[0] = bq; qa.out[0] = Qh;
  qa.A[1] = kb; qa.W[1] = Wkb; qa.bias[1] = bk; qa.out[1] = Kh;
  qa.A[2] = vb; qa.W[2] = Wvb; qa.bias[2] = bv; qa.out[2] = VT;
  qkv_gemm<<<dim3(M_TOT / BM, Dmod / BN, 3), blk, 0, stream>>>(qa, C_SC);

  attn_fwd<<<dim3(2048), blk, 0, stream>>>(Qh, Kh, VT, X);

  out_gemm<<<dim3(M_TOT / BM, Dmod / BN), blk, 0, stream>>>(X, Wob, out);
}